// Round 3
// baseline (603.183 us; speedup 1.0000x reference)
//
#include <hip/hip_runtime.h>
#include <math.h>

typedef __bf16 bf16;
typedef __bf16 bf16x8 __attribute__((ext_vector_type(8)));
typedef __bf16 bf16x4 __attribute__((ext_vector_type(4)));
typedef float f32x4 __attribute__((ext_vector_type(4)));

#define CC 256
#define BB 16
#define HH 56
#define WW 56
#define HWSZ 3136   // 56*56
#define EPS 1e-5f

// ws byte offsets
#define OFF_SCALE 0
#define OFF_SUMS  16384
#define OFF_WBF1  32768
#define OFF_WBF2  163840
#define OFF_WDW   294912        // 35*256 bf16 (wcomb 25 | wxz 5 | wyz 5)
#define OFF_BNC   312832        // 8*256 f32
#define OFF_OUT2  321024        // NEL bf16

// bf16x4 -> f32x4 via bit ops (1 VALU/element; bf16 f32 = bits<<16)
__device__ __forceinline__ f32x4 cvt4(bf16x4 v) {
    union { bf16x4 b; unsigned int u[2]; } q; q.b = v;
    f32x4 r;
    r[0] = __uint_as_float(q.u[0] << 16);
    r[1] = __uint_as_float(q.u[0] & 0xffff0000u);
    r[2] = __uint_as_float(q.u[1] << 16);
    r[3] = __uint_as_float(q.u[1] & 0xffff0000u);
    return r;
}

// ---------------------------------------------------------------------------
// K0: precast weights -> bf16, combined DW taps + BN consts, zero sums.
// ---------------------------------------------------------------------------
__global__ __launch_bounds__(256) void precast(
    const float* __restrict__ w1, const float* __restrict__ w2,
    const float* __restrict__ xy3, const float* __restrict__ xy5,
    const float* __restrict__ xz3, const float* __restrict__ xz5,
    const float* __restrict__ yz3, const float* __restrict__ yz5,
    const float* __restrict__ gxy, const float* __restrict__ bxy,
    const float* __restrict__ mxy, const float* __restrict__ vxy,
    const float* __restrict__ gxz, const float* __restrict__ bxz,
    const float* __restrict__ mxz, const float* __restrict__ vxz,
    const float* __restrict__ gyz, const float* __restrict__ byz,
    const float* __restrict__ myz, const float* __restrict__ vyz,
    const float* __restrict__ alpha, const float* __restrict__ beta,
    bf16* __restrict__ wbf1, bf16* __restrict__ wbf2,
    bf16* __restrict__ wdw, float* __restrict__ bnc,
    float* __restrict__ sums)
{
    const int blk = blockIdx.x, t = threadIdx.x;
    if (blk < 128) {
        int i = blk * 512 + t * 2;
        wbf1[i] = (bf16)w1[i]; wbf1[i + 1] = (bf16)w1[i + 1];
    } else if (blk < 256) {
        int i = (blk - 128) * 512 + t * 2;
        wbf2[i] = (bf16)w2[i]; wbf2[i + 1] = (bf16)w2[i + 1];
    } else {
        const int c = t;
#pragma unroll
        for (int dh = 0; dh < 5; ++dh)
#pragma unroll
            for (int dw = 0; dw < 5; ++dw) {
                float v = xy5[c * 25 + dh * 5 + dw];
                if (dh >= 1 && dh <= 3 && dw >= 1 && dw <= 3)
                    v += xy3[c * 9 + (dh - 1) * 3 + (dw - 1)];
                wdw[(dh * 5 + dw) * CC + c] = (bf16)v;
            }
#pragma unroll
        for (int d = 0; d < 5; ++d) {
            float v = xz5[c * 5 + d];
            if (d >= 1 && d <= 3) v += xz3[c * 3 + d - 1];
            wdw[(25 + d) * CC + c] = (bf16)v;
            float u = yz5[c * 5 + d];
            if (d >= 1 && d <= 3) u += yz3[c * 3 + d - 1];
            wdw[(30 + d) * CC + c] = (bf16)u;
        }
        float s;
        s = gxy[c] * rsqrtf(vxy[c] + EPS); bnc[0*CC+c] = s; bnc[1*CC+c] = bxy[c] - mxy[c]*s;
        s = gxz[c] * rsqrtf(vxz[c] + EPS); bnc[2*CC+c] = s; bnc[3*CC+c] = bxz[c] - mxz[c]*s;
        s = gyz[c] * rsqrtf(vyz[c] + EPS); bnc[4*CC+c] = s; bnc[5*CC+c] = byz[c] - myz[c]*s;
        bnc[6*CC+c] = alpha[c]; bnc[7*CC+c] = beta[c];
        for (int i = t; i < BB * CC; i += 256) sums[i] = 0.f;
    }
}

// ---------------------------------------------------------------------------
// K1: pw1 GEMM.  mid[b][hw][co] = sum_ci x[b][ci][hw] * w[co][ci]  (bf16 out)
// K-split weight preload (aq[4][4] twice) -> 3 blocks/CU.
// ---------------------------------------------------------------------------
__global__ __launch_bounds__(256, 3) void pw_gemm1(
    const float* __restrict__ in, const bf16* __restrict__ wbf,
    bf16* __restrict__ mid)
{
    __shared__ __align__(16) bf16 XT[64][264];   // [hw][ci], pad 264
    const int hw0 = blockIdx.x * 64;
    const int b   = blockIdx.y;
    const int t   = threadIdx.x;
    const int lane = t & 63, wv = t >> 6;
    const int q = lane >> 4, n = lane & 15;
    const int co_w = wv * 64;

    // preload K-half 0 of the weight fragments
    bf16x8 aq[4][4];
    const bf16* wp[4];
#pragma unroll
    for (int cf = 0; cf < 4; ++cf) {
        wp[cf] = wbf + (size_t)(co_w + cf * 16 + n) * CC + q * 8;
#pragma unroll
        for (int kx = 0; kx < 4; ++kx)
            aq[cf][kx] = *(const bf16x8*)(wp[cf] + kx * 32);
    }

    {   // stage x tile (fp32 NCHW) -> XT[hw][ci] bf16
        const int hwg = (t & 15) * 4;
        const int cig = (t >> 4) * 4;
        const float* base = in + (size_t)b * CC * HWSZ + hw0 + hwg;
#pragma unroll
        for (int pass = 0; pass < 4; ++pass) {
            const int ci0 = pass * 64 + cig;
            f32x4 v[4];
#pragma unroll
            for (int i = 0; i < 4; ++i)
                v[i] = *(const f32x4*)(base + (size_t)(ci0 + i) * HWSZ);
#pragma unroll
            for (int j = 0; j < 4; ++j) {
                bf16x4 r = {(bf16)v[0][j], (bf16)v[1][j], (bf16)v[2][j], (bf16)v[3][j]};
                *(bf16x4*)(&XT[hwg + j][ci0]) = r;
            }
        }
    }
    __syncthreads();

    f32x4 acc[4][4] = {};   // [cf][hf]
#pragma unroll
    for (int half = 0; half < 2; ++half) {
#pragma unroll
        for (int kx = 0; kx < 4; ++kx) {
            const int kk = half * 4 + kx;
            bf16x8 bq[4];
#pragma unroll
            for (int hf = 0; hf < 4; ++hf)
                bq[hf] = *(const bf16x8*)(&XT[hf * 16 + n][kk * 32 + q * 8]);
#pragma unroll
            for (int cf = 0; cf < 4; ++cf)
#pragma unroll
                for (int hf = 0; hf < 4; ++hf)
                    acc[cf][hf] = __builtin_amdgcn_mfma_f32_16x16x32_bf16(
                        aq[cf][kx], bq[hf], acc[cf][hf], 0, 0, 0);
        }
        if (half == 0) {    // reload K-half 1 fragments
#pragma unroll
            for (int cf = 0; cf < 4; ++cf)
#pragma unroll
                for (int kx = 0; kx < 4; ++kx)
                    aq[cf][kx] = *(const bf16x8*)(wp[cf] + 128 + kx * 32);
        }
    }

    bf16* ob = mid + ((size_t)b * HWSZ + hw0) * CC;
#pragma unroll
    for (int cf = 0; cf < 4; ++cf) {
        const int co4 = co_w + cf * 16 + q * 4;
#pragma unroll
        for (int hf = 0; hf < 4; ++hf) {
            bf16x4 r = {(bf16)acc[cf][hf][0], (bf16)acc[cf][hf][1],
                        (bf16)acc[cf][hf][2], (bf16)acc[cf][hf][3]};
            *(bf16x4*)(ob + (size_t)(hf * 16 + n) * CC + co4) = r;
        }
    }
}

// ---------------------------------------------------------------------------
// K2: fused depthwise + BN + ReLU + gate, NHWC.
// 4 ch/thread (c0 = 4*lane), thread tile 2h x 4w, f32 weights in LDS.
// Manual 2-deep software pipeline: loads for row k+2 issued before
// computing row k (double-buffered bf16x4 raw rows).
// grid (4, 28, 16); block 256 = 4 waves; wave wv covers w = bx*16+4*wv+[0,4).
// ---------------------------------------------------------------------------
__global__ __launch_bounds__(256, 2) void dwfuse(
    const bf16* __restrict__ mid, const bf16* __restrict__ wdw,
    const float* __restrict__ bnc, bf16* __restrict__ top)
{
    __shared__ __align__(16) float lwf[35 * 256];   // 35840 B
    const int t = threadIdx.x;
#pragma unroll
    for (int k = 0; k < 35; ++k)
        lwf[k * 256 + t] = (float)wdw[k * 256 + t];
    __syncthreads();

    const int lane = t & 63;
    const int wb = blockIdx.x * 16 + (t >> 6) * 4;   // wave's base output w
    const int h0 = blockIdx.y * 2;
    const size_t plane = (size_t)blockIdx.z * HWSZ;
    const int c0 = lane * 4;
    const bf16* gbase = mid + plane * CC + c0;

    f32x4 axy[2][4] = {}, axz[2][4] = {}, ayz[2][4] = {};   // [ph][pw]
    bf16x4 rA[8], rB[8];

#define LOADROW(DHH, BUF) do {                                               \
    const int hh_ = h0 - 2 + (DHH);                                          \
    if ((unsigned)hh_ < (unsigned)HH) {                                      \
        const bf16* rp_ = gbase + (size_t)hh_ * WW * CC;                     \
        _Pragma("unroll")                                                    \
        for (int wc_ = 0; wc_ < 8; ++wc_) {                                  \
            const int ww_ = wb - 2 + wc_;                                    \
            if ((unsigned)ww_ < (unsigned)WW)                                \
                BUF[wc_] = *(const bf16x4*)(rp_ + (size_t)ww_ * CC);         \
            else { bf16x4 z_ = {}; BUF[wc_] = z_; }                          \
        }                                                                    \
    } else {                                                                 \
        _Pragma("unroll")                                                    \
        for (int wc_ = 0; wc_ < 8; ++wc_) { bf16x4 z_ = {}; BUF[wc_] = z_; } \
    }                                                                        \
} while (0)

#define COMPROW(DHH, BUF) do {                                               \
    f32x4 fv_[8];                                                            \
    _Pragma("unroll")                                                        \
    for (int wc_ = 0; wc_ < 8; ++wc_) fv_[wc_] = cvt4(BUF[wc_]);             \
    _Pragma("unroll")                                                        \
    for (int ph_ = 0; ph_ < 2; ++ph_) {                                      \
        const int dh_ = (DHH) - ph_;                                         \
        if (dh_ < 0 || dh_ > 4) continue;                                    \
        _Pragma("unroll")                                                    \
        for (int dw_ = 0; dw_ < 5; ++dw_) {                                  \
            const f32x4 wt_ = *(const f32x4*)(&lwf[(dh_ * 5 + dw_) * CC + c0]); \
            _Pragma("unroll")                                                \
            for (int pw_ = 0; pw_ < 4; ++pw_)                                \
                axy[ph_][pw_] += wt_ * fv_[dw_ + pw_];                       \
        }                                                                    \
        if (dh_ == 2) {                                                      \
            _Pragma("unroll")                                                \
            for (int dw_ = 0; dw_ < 5; ++dw_) {                              \
                const f32x4 wz_ = *(const f32x4*)(&lwf[(25 + dw_) * CC + c0]); \
                _Pragma("unroll")                                            \
                for (int pw_ = 0; pw_ < 4; ++pw_)                            \
                    axz[ph_][pw_] += wz_ * fv_[dw_ + pw_];                   \
            }                                                                \
        }                                                                    \
        {                                                                    \
            const f32x4 wy_ = *(const f32x4*)(&lwf[(30 + dh_) * CC + c0]);   \
            _Pragma("unroll")                                                \
            for (int pw_ = 0; pw_ < 4; ++pw_)                                \
                ayz[ph_][pw_] += wy_ * fv_[2 + pw_];                         \
        }                                                                    \
    }                                                                        \
} while (0)

    LOADROW(0, rA);
    LOADROW(1, rB);
    COMPROW(0, rA);
    LOADROW(2, rA);
    COMPROW(1, rB);
    LOADROW(3, rB);
    COMPROW(2, rA);
    LOADROW(4, rA);
    COMPROW(3, rB);
    LOADROW(5, rB);
    COMPROW(4, rA);
    COMPROW(5, rB);

#undef LOADROW
#undef COMPROW

    // BN / gate consts (global, L1-cached, f32x4 aligned at c0 = 4*lane)
    const f32x4 sxy = *(const f32x4*)(bnc + 0 * CC + c0);
    const f32x4 hxy = *(const f32x4*)(bnc + 1 * CC + c0);
    const f32x4 sxz = *(const f32x4*)(bnc + 2 * CC + c0);
    const f32x4 hxz = *(const f32x4*)(bnc + 3 * CC + c0);
    const f32x4 syz = *(const f32x4*)(bnc + 4 * CC + c0);
    const f32x4 hyz = *(const f32x4*)(bnc + 5 * CC + c0);
    const f32x4 al  = *(const f32x4*)(bnc + 6 * CC + c0);
    const f32x4 be  = *(const f32x4*)(bnc + 7 * CC + c0);

#pragma unroll
    for (int ph = 0; ph < 2; ++ph)
#pragma unroll
        for (int pw = 0; pw < 4; ++pw) {
            const int w = wb + pw;
            const f32x4 txy = axy[ph][pw] * sxy + hxy;
            const f32x4 txz = axz[ph][pw] * sxz + hxz;
            const f32x4 tyz = ayz[ph][pw] * syz + hyz;
            bf16x4 r;
#pragma unroll
            for (int j = 0; j < 4; ++j) {
                const float fxy = fmaxf(txy[j], 0.f);
                const float fxz = fmaxf(txz[j], 0.f);
                const float fyz = fmaxf(tyz[j], 0.f);
                const float z   = al[j] * fxz + be[j] * fyz;
                const float g   = 1.f / (1.f + __expf(-z));
                r[j] = (bf16)(fxy * g);   // fxy>=0, g>0 -> relu is a no-op
            }
            if (w < WW)
                *(bf16x4*)(top + (plane + (size_t)(h0 + ph) * WW + w) * CC + c0) = r;
        }
}

// ---------------------------------------------------------------------------
// K3: pw2 GEMM + BN + ReLU + SE partial sums.  Same K-split frame as K1.
// ---------------------------------------------------------------------------
__global__ __launch_bounds__(256, 3) void pw_gemm2(
    const bf16* __restrict__ top, const bf16* __restrict__ wbf,
    const float* __restrict__ g2, const float* __restrict__ b2,
    const float* __restrict__ m2, const float* __restrict__ v2,
    bf16* __restrict__ out2, float* __restrict__ sums)
{
    __shared__ __align__(16) bf16 XT[64][264];
    const int hw0 = blockIdx.x * 64;
    const int b   = blockIdx.y;
    const int t   = threadIdx.x;
    const int lane = t & 63, wv = t >> 6;
    const int q = lane >> 4, n = lane & 15;
    const int co_w = wv * 64;

    bf16x8 aq[4][4];
    const bf16* wp[4];
#pragma unroll
    for (int cf = 0; cf < 4; ++cf) {
        wp[cf] = wbf + (size_t)(co_w + cf * 16 + n) * CC + q * 8;
#pragma unroll
        for (int kx = 0; kx < 4; ++kx)
            aq[cf][kx] = *(const bf16x8*)(wp[cf] + kx * 32);
    }

    {   // straight copy staging (already NHWC): 64 bf16 per thread
        const int hw_r = t >> 2;
        const int k0   = (t & 3) * 64;
        const bf16* src = top + ((size_t)b * HWSZ + hw0 + hw_r) * CC + k0;
#pragma unroll
        for (int j = 0; j < 8; ++j)
            *(bf16x8*)(&XT[hw_r][k0 + j * 8]) = *(const bf16x8*)(src + j * 8);
    }
    __syncthreads();

    f32x4 acc[4][4] = {};
#pragma unroll
    for (int half = 0; half < 2; ++half) {
#pragma unroll
        for (int kx = 0; kx < 4; ++kx) {
            const int kk = half * 4 + kx;
            bf16x8 bq[4];
#pragma unroll
            for (int hf = 0; hf < 4; ++hf)
                bq[hf] = *(const bf16x8*)(&XT[hf * 16 + n][kk * 32 + q * 8]);
#pragma unroll
            for (int cf = 0; cf < 4; ++cf)
#pragma unroll
                for (int hf = 0; hf < 4; ++hf)
                    acc[cf][hf] = __builtin_amdgcn_mfma_f32_16x16x32_bf16(
                        aq[cf][kx], bq[hf], acc[cf][hf], 0, 0, 0);
        }
        if (half == 0) {
#pragma unroll
            for (int cf = 0; cf < 4; ++cf)
#pragma unroll
                for (int kx = 0; kx < 4; ++kx)
                    aq[cf][kx] = *(const bf16x8*)(wp[cf] + 128 + kx * 32);
        }
    }

    bf16* ob = out2 + ((size_t)b * HWSZ + hw0) * CC;
#pragma unroll
    for (int cf = 0; cf < 4; ++cf) {
        const int co4 = co_w + cf * 16 + q * 4;
        f32x4 g = *(const f32x4*)(g2 + co4);
        f32x4 bb = *(const f32x4*)(b2 + co4);
        f32x4 mm = *(const f32x4*)(m2 + co4);
        f32x4 vv = *(const f32x4*)(v2 + co4);
        f32x4 sc, sh;
#pragma unroll
        for (int r = 0; r < 4; ++r) {
            sc[r] = g[r] * rsqrtf(vv[r] + EPS);
            sh[r] = bb[r] - mm[r] * sc[r];
        }
        f32x4 rs = {};
#pragma unroll
        for (int hf = 0; hf < 4; ++hf) {
            bf16x4 r4;
#pragma unroll
            for (int r = 0; r < 4; ++r) {
                float v = fmaxf(acc[cf][hf][r] * sc[r] + sh[r], 0.f);
                rs[r] += v;
                r4[r] = (bf16)v;
            }
            *(bf16x4*)(ob + (size_t)(hf * 16 + n) * CC + co4) = r4;
        }
#pragma unroll
        for (int msk = 1; msk < 16; msk <<= 1)
#pragma unroll
            for (int r = 0; r < 4; ++r) rs[r] += __shfl_xor(rs[r], msk);
        if (n == 0) {
#pragma unroll
            for (int r = 0; r < 4; ++r)
                atomicAdd(&sums[b * CC + co4 + r], rs[r]);
        }
    }
}

// ---------------------------------------------------------------------------
// K5: SE FC (redundant per block, tiny) + apply + residual add + transpose.
// out[b][c][hw] = out2[b][hw][c] * scale[b,c] + x[b][c][hw]
// ---------------------------------------------------------------------------
__global__ __launch_bounds__(256) void se_apply(
    const bf16* __restrict__ out2, const float* __restrict__ x,
    const float* __restrict__ sums,
    const float* __restrict__ w1, const float* __restrict__ b1,
    const float* __restrict__ w2, const float* __restrict__ b2,
    float* __restrict__ out)
{
    __shared__ float TT[64 * 68];   // [c_local][hw_local], pad 68
    __shared__ float mean[256];
    __shared__ float hid[16];
    __shared__ __align__(16) float scl[64];
    const int hw0 = blockIdx.x * 64;
    const int c0  = blockIdx.y * 64;
    const int b   = blockIdx.z;
    const int t   = threadIdx.x;

    // --- SE FC (each block computes its 64-channel slice of scale) ---
    mean[t] = sums[b * CC + t] * (1.f / (float)HWSZ);
    __syncthreads();
    {
        const int m = t >> 4, l = t & 15;
        const float* wr = w1 + m * CC + l * 16;
        const float* mr = mean + l * 16;
        float h = 0.f;
#pragma unroll
        for (int j = 0; j < 16; ++j) h += wr[j] * mr[j];
#pragma unroll
        for (int msk = 1; msk < 16; msk <<= 1) h += __shfl_xor(h, msk);
        if (l == 0) hid[m] = fmaxf(h + b1[m], 0.f);
    }
    __syncthreads();
    if (t < 64) {
        const int c = c0 + t;
        float v = b2[c];
#pragma unroll
        for (int md = 0; md < 16; ++md) v += w2[c * 16 + md] * hid[md];
        scl[t] = 1.f / (1.f + __expf(-v));
    }
    __syncthreads();

    // --- scale + transpose via LDS ---
    {
        const int hw_r = t >> 2;
        const int coff = (t & 3) * 16;
        const bf16* p = out2 + ((size_t)b * HWSZ + hw0 + hw_r) * CC + c0 + coff;
        bf16x8 u0 = *(const bf16x8*)(p);
        bf16x8 u1 = *(const bf16x8*)(p + 8);
        f32x4 s0 = *(const f32x4*)(&scl[coff]);
        f32x4 s1 = *(const f32x4*)(&scl[coff + 4]);
        f32x4 s2 = *(const f32x4*)(&scl[coff + 8]);
        f32x4 s3 = *(const f32x4*)(&scl[coff + 12]);
#pragma unroll
        for (int j = 0; j < 4; ++j) {
            TT[(coff + j)      * 68 + hw_r] = (float)u0[j]     * s0[j];
            TT[(coff + 4 + j)  * 68 + hw_r] = (float)u0[4 + j] * s1[j];
            TT[(coff + 8 + j)  * 68 + hw_r] = (float)u1[j]     * s2[j];
            TT[(coff + 12 + j) * 68 + hw_r] = (float)u1[4 + j] * s3[j];
        }
    }
    __syncthreads();
    {
        const int c_r   = t >> 2;
        const int hwoff = (t & 3) * 16;
        const size_t go = ((size_t)b * CC + c0 + c_r) * HWSZ + hw0 + hwoff;
#pragma unroll
        for (int v = 0; v < 4; ++v) {
            f32x4 tv = *(const f32x4*)(&TT[c_r * 68 + hwoff + v * 4]);
            f32x4 xv = *(const f32x4*)(x + go + v * 4);
#pragma unroll
            for (int j = 0; j < 4; ++j) tv[j] += xv[j];
            *(f32x4*)(out + go + v * 4) = tv;
        }
    }
}

// ---------------------------------------------------------------------------
extern "C" void kernel_launch(void* const* d_in, const int* in_sizes, int n_in,
                              void* d_out, int out_size, void* d_ws, size_t ws_size,
                              hipStream_t stream)
{
    const float* x      = (const float*)d_in[0];
    const float* pw1_w  = (const float*)d_in[1];
    const float* xy3_w  = (const float*)d_in[2];
    const float* xy5_w  = (const float*)d_in[3];
    const float* bnxy_g = (const float*)d_in[4];
    const float* bnxy_b = (const float*)d_in[5];
    const float* bnxy_m = (const float*)d_in[6];
    const float* bnxy_v = (const float*)d_in[7];
    const float* xz3_w  = (const float*)d_in[8];
    const float* xz5_w  = (const float*)d_in[9];
    const float* bnxz_g = (const float*)d_in[10];
    const float* bnxz_b = (const float*)d_in[11];
    const float* bnxz_m = (const float*)d_in[12];
    const float* bnxz_v = (const float*)d_in[13];
    const float* yz3_w  = (const float*)d_in[14];
    const float* yz5_w  = (const float*)d_in[15];
    const float* bnyz_g = (const float*)d_in[16];
    const float* bnyz_b = (const float*)d_in[17];
    const float* bnyz_m = (const float*)d_in[18];
    const float* bnyz_v = (const float*)d_in[19];
    const float* alpha  = (const float*)d_in[20];
    const float* beta   = (const float*)d_in[21];
    const float* pw2_w  = (const float*)d_in[22];
    const float* bn2_g  = (const float*)d_in[23];
    const float* bn2_b  = (const float*)d_in[24];
    const float* bn2_m  = (const float*)d_in[25];
    const float* bn2_v  = (const float*)d_in[26];
    const float* fc1_w  = (const float*)d_in[27];
    const float* fc1_b  = (const float*)d_in[28];
    const float* fc2_w  = (const float*)d_in[29];
    const float* fc2_b  = (const float*)d_in[30];

    const size_t NEL = (size_t)BB * CC * HWSZ;   // 12,845,056
    char* ws = (char*)d_ws;
    float* sums  = (float*)(ws + OFF_SUMS);
    bf16*  wbf1  = (bf16*) (ws + OFF_WBF1);
    bf16*  wbf2  = (bf16*) (ws + OFF_WBF2);
    bf16*  wdw   = (bf16*) (ws + OFF_WDW);
    float* bnc   = (float*)(ws + OFF_BNC);
    bf16*  out2  = (bf16*) (ws + OFF_OUT2);
    bf16*  mid   = (bf16*)d_out;           // d_out as scratch: mid | top
    bf16*  top   = (bf16*)d_out + NEL;

    precast<<<257, 256, 0, stream>>>(pw1_w, pw2_w,
        xy3_w, xy5_w, xz3_w, xz5_w, yz3_w, yz5_w,
        bnxy_g, bnxy_b, bnxy_m, bnxy_v,
        bnxz_g, bnxz_b, bnxz_m, bnxz_v,
        bnyz_g, bnyz_b, bnyz_m, bnyz_v,
        alpha, beta, wbf1, wbf2, wdw, bnc, sums);

    pw_gemm1<<<dim3(49, 16), 256, 0, stream>>>(x, wbf1, mid);
    dwfuse<<<dim3(4, 28, 16), 256, 0, stream>>>(mid, wdw, bnc, top);
    pw_gemm2<<<dim3(49, 16), 256, 0, stream>>>(top, wbf2, bn2_g, bn2_b,
                                               bn2_m, bn2_v, out2, sums);
    se_apply<<<dim3(49, 4, 16), 256, 0, stream>>>(out2, x, sums,
        fc1_w, fc1_b, fc2_w, fc2_b, (float*)d_out);
}

// Round 4
// 262.342 us; speedup vs baseline: 2.2992x; 2.2992x over previous
//
#include <hip/hip_runtime.h>
#include <math.h>

typedef __bf16 bf16;
typedef __bf16 bf16x8 __attribute__((ext_vector_type(8)));
typedef __bf16 bf16x4 __attribute__((ext_vector_type(4)));
typedef float f32x4 __attribute__((ext_vector_type(4)));

#define CC 256
#define BB 16
#define HH 56
#define WW 56
#define HWSZ 3136   // 56*56
#define EPS 1e-5f

// ws byte offsets
#define OFF_SCALE 0
#define OFF_SUMS  16384
#define OFF_WBF1  32768
#define OFF_WBF2  163840
#define OFF_WDW   294912        // 35*256 bf16 (wcomb 25 | wxz 5 | wyz 5)
#define OFF_BNC   312832        // 8*256 f32
#define OFF_OUT2  321024        // NEL bf16

// bf16x4 -> f32x4 via bit ops (1 VALU/element; bf16 f32 = bits<<16)
__device__ __forceinline__ f32x4 cvt4(bf16x4 v) {
    union { bf16x4 b; unsigned int u[2]; } q; q.b = v;
    f32x4 r;
    r[0] = __uint_as_float(q.u[0] << 16);
    r[1] = __uint_as_float(q.u[0] & 0xffff0000u);
    r[2] = __uint_as_float(q.u[1] << 16);
    r[3] = __uint_as_float(q.u[1] & 0xffff0000u);
    return r;
}

// ---------------------------------------------------------------------------
// K0: precast weights -> bf16, combined DW taps + BN consts, zero sums.
// ---------------------------------------------------------------------------
__global__ __launch_bounds__(256) void precast(
    const float* __restrict__ w1, const float* __restrict__ w2,
    const float* __restrict__ xy3, const float* __restrict__ xy5,
    const float* __restrict__ xz3, const float* __restrict__ xz5,
    const float* __restrict__ yz3, const float* __restrict__ yz5,
    const float* __restrict__ gxy, const float* __restrict__ bxy,
    const float* __restrict__ mxy, const float* __restrict__ vxy,
    const float* __restrict__ gxz, const float* __restrict__ bxz,
    const float* __restrict__ mxz, const float* __restrict__ vxz,
    const float* __restrict__ gyz, const float* __restrict__ byz,
    const float* __restrict__ myz, const float* __restrict__ vyz,
    const float* __restrict__ alpha, const float* __restrict__ beta,
    bf16* __restrict__ wbf1, bf16* __restrict__ wbf2,
    bf16* __restrict__ wdw, float* __restrict__ bnc,
    float* __restrict__ sums)
{
    const int blk = blockIdx.x, t = threadIdx.x;
    if (blk < 128) {
        int i = blk * 512 + t * 2;
        wbf1[i] = (bf16)w1[i]; wbf1[i + 1] = (bf16)w1[i + 1];
    } else if (blk < 256) {
        int i = (blk - 128) * 512 + t * 2;
        wbf2[i] = (bf16)w2[i]; wbf2[i + 1] = (bf16)w2[i + 1];
    } else {
        const int c = t;
#pragma unroll
        for (int dh = 0; dh < 5; ++dh)
#pragma unroll
            for (int dw = 0; dw < 5; ++dw) {
                float v = xy5[c * 25 + dh * 5 + dw];
                if (dh >= 1 && dh <= 3 && dw >= 1 && dw <= 3)
                    v += xy3[c * 9 + (dh - 1) * 3 + (dw - 1)];
                wdw[(dh * 5 + dw) * CC + c] = (bf16)v;
            }
#pragma unroll
        for (int d = 0; d < 5; ++d) {
            float v = xz5[c * 5 + d];
            if (d >= 1 && d <= 3) v += xz3[c * 3 + d - 1];
            wdw[(25 + d) * CC + c] = (bf16)v;
            float u = yz5[c * 5 + d];
            if (d >= 1 && d <= 3) u += yz3[c * 3 + d - 1];
            wdw[(30 + d) * CC + c] = (bf16)u;
        }
        float s;
        s = gxy[c] * rsqrtf(vxy[c] + EPS); bnc[0*CC+c] = s; bnc[1*CC+c] = bxy[c] - mxy[c]*s;
        s = gxz[c] * rsqrtf(vxz[c] + EPS); bnc[2*CC+c] = s; bnc[3*CC+c] = bxz[c] - mxz[c]*s;
        s = gyz[c] * rsqrtf(vyz[c] + EPS); bnc[4*CC+c] = s; bnc[5*CC+c] = byz[c] - myz[c]*s;
        bnc[6*CC+c] = alpha[c]; bnc[7*CC+c] = beta[c];
        for (int i = t; i < BB * CC; i += 256) sums[i] = 0.f;
    }
}

// ---------------------------------------------------------------------------
// K1: pw1 GEMM.  mid[b][hw][co] = sum_ci x[b][ci][hw] * w[co][ci]  (bf16 out)
// K-split weight preload (aq[4][4] twice) -> 3 blocks/CU.
// ---------------------------------------------------------------------------
__global__ __launch_bounds__(256, 3) void pw_gemm1(
    const float* __restrict__ in, const bf16* __restrict__ wbf,
    bf16* __restrict__ mid)
{
    __shared__ __align__(16) bf16 XT[64][264];   // [hw][ci], pad 264
    const int hw0 = blockIdx.x * 64;
    const int b   = blockIdx.y;
    const int t   = threadIdx.x;
    const int lane = t & 63, wv = t >> 6;
    const int q = lane >> 4, n = lane & 15;
    const int co_w = wv * 64;

    // preload K-half 0 of the weight fragments
    bf16x8 aq[4][4];
    const bf16* wp[4];
#pragma unroll
    for (int cf = 0; cf < 4; ++cf) {
        wp[cf] = wbf + (size_t)(co_w + cf * 16 + n) * CC + q * 8;
#pragma unroll
        for (int kx = 0; kx < 4; ++kx)
            aq[cf][kx] = *(const bf16x8*)(wp[cf] + kx * 32);
    }

    {   // stage x tile (fp32 NCHW) -> XT[hw][ci] bf16
        const int hwg = (t & 15) * 4;
        const int cig = (t >> 4) * 4;
        const float* base = in + (size_t)b * CC * HWSZ + hw0 + hwg;
#pragma unroll
        for (int pass = 0; pass < 4; ++pass) {
            const int ci0 = pass * 64 + cig;
            f32x4 v[4];
#pragma unroll
            for (int i = 0; i < 4; ++i)
                v[i] = *(const f32x4*)(base + (size_t)(ci0 + i) * HWSZ);
#pragma unroll
            for (int j = 0; j < 4; ++j) {
                bf16x4 r = {(bf16)v[0][j], (bf16)v[1][j], (bf16)v[2][j], (bf16)v[3][j]};
                *(bf16x4*)(&XT[hwg + j][ci0]) = r;
            }
        }
    }
    __syncthreads();

    f32x4 acc[4][4] = {};   // [cf][hf]
#pragma unroll
    for (int half = 0; half < 2; ++half) {
#pragma unroll
        for (int kx = 0; kx < 4; ++kx) {
            const int kk = half * 4 + kx;
            bf16x8 bq[4];
#pragma unroll
            for (int hf = 0; hf < 4; ++hf)
                bq[hf] = *(const bf16x8*)(&XT[hf * 16 + n][kk * 32 + q * 8]);
#pragma unroll
            for (int cf = 0; cf < 4; ++cf)
#pragma unroll
                for (int hf = 0; hf < 4; ++hf)
                    acc[cf][hf] = __builtin_amdgcn_mfma_f32_16x16x32_bf16(
                        aq[cf][kx], bq[hf], acc[cf][hf], 0, 0, 0);
        }
        if (half == 0) {    // reload K-half 1 fragments
#pragma unroll
            for (int cf = 0; cf < 4; ++cf)
#pragma unroll
                for (int kx = 0; kx < 4; ++kx)
                    aq[cf][kx] = *(const bf16x8*)(wp[cf] + 128 + kx * 32);
        }
    }

    bf16* ob = mid + ((size_t)b * HWSZ + hw0) * CC;
#pragma unroll
    for (int cf = 0; cf < 4; ++cf) {
        const int co4 = co_w + cf * 16 + q * 4;
#pragma unroll
        for (int hf = 0; hf < 4; ++hf) {
            bf16x4 r = {(bf16)acc[cf][hf][0], (bf16)acc[cf][hf][1],
                        (bf16)acc[cf][hf][2], (bf16)acc[cf][hf][3]};
            *(bf16x4*)(ob + (size_t)(hf * 16 + n) * CC + co4) = r;
        }
    }
}

// ---------------------------------------------------------------------------
// K2: fused depthwise + BN + ReLU + gate, NHWC.
// 4 ch/thread (c0 = 4*lane), thread tile 2h x 2w, f32 weights in LDS.
// ALL 36 raw input loads issued up-front (latency hides under the weight
// staging + barrier); sched_barrier pins them; compute is then LDS+VALU only.
// grid (7, 28, 16); block 256 = 4 waves.
// ---------------------------------------------------------------------------
__global__ __launch_bounds__(256, 2) void dwfuse(
    const bf16* __restrict__ mid, const bf16* __restrict__ wdw,
    const float* __restrict__ bnc, bf16* __restrict__ top)
{
    __shared__ __align__(16) float lwf[35 * 256];   // 35840 B
    const int t = threadIdx.x;
    const int lane = t & 63;
    const int wb = blockIdx.x * 8 + (t >> 6) * 2;   // wave's base output w
    const int h0 = blockIdx.y * 2;
    const size_t plane = (size_t)blockIdx.z * HWSZ;
    const int c0 = lane * 4;
    const bf16* gbase = mid + plane * CC + c0;

    // 1) issue ALL 36 raw loads first; zero-fill OOB. Static indexing only.
    bf16x4 raw[6][6];
#pragma unroll
    for (int r = 0; r < 6; ++r) {
        const int hh = h0 - 2 + r;
        const bool hok = (unsigned)hh < (unsigned)HH;
        const bf16* rp = gbase + (ptrdiff_t)hh * (WW * CC);
#pragma unroll
        for (int wc = 0; wc < 6; ++wc) {
            const int ww = wb - 2 + wc;
            bf16x4 v = {};
            if (hok && (unsigned)ww < (unsigned)WW)
                v = *(const bf16x4*)(rp + (ptrdiff_t)ww * CC);
            raw[r][wc] = v;
        }
    }
    __builtin_amdgcn_sched_barrier(0);   // keep loads above everything below

    // 2) weight staging (global->LDS as f32); barrier hides load latency
#pragma unroll
    for (int k = 0; k < 35; ++k)
        lwf[k * 256 + t] = (float)wdw[k * 256 + t];
    __syncthreads();

    // 3) compute: pure LDS + packed-f32 FMA
    f32x4 axy[2][2] = {}, axz[2][2] = {}, ayz[2][2] = {};   // [ph][pw]
#pragma unroll
    for (int r = 0; r < 6; ++r) {
        f32x4 fv[6];
#pragma unroll
        for (int wc = 0; wc < 6; ++wc) fv[wc] = cvt4(raw[r][wc]);
#pragma unroll
        for (int ph = 0; ph < 2; ++ph) {
            const int dh = r - ph;                   // tap row for pixel h0+ph
            if (dh < 0 || dh > 4) continue;          // compile-time
#pragma unroll
            for (int dw = 0; dw < 5; ++dw) {
                const f32x4 wt = *(const f32x4*)(&lwf[(dh * 5 + dw) * CC + c0]);
                axy[ph][0] += wt * fv[dw];
                axy[ph][1] += wt * fv[dw + 1];
            }
            if (dh == 2) {                           // xz: center row only
#pragma unroll
                for (int dw = 0; dw < 5; ++dw) {
                    const f32x4 wz = *(const f32x4*)(&lwf[(25 + dw) * CC + c0]);
                    axz[ph][0] += wz * fv[dw];
                    axz[ph][1] += wz * fv[dw + 1];
                }
            }
            {                                        // yz: center column only
                const f32x4 wy = *(const f32x4*)(&lwf[(30 + dh) * CC + c0]);
                ayz[ph][0] += wy * fv[2];
                ayz[ph][1] += wy * fv[3];
            }
        }
    }

    // BN / gate consts (global, L1-cached, f32x4 aligned at c0 = 4*lane)
    const f32x4 sxy = *(const f32x4*)(bnc + 0 * CC + c0);
    const f32x4 hxy = *(const f32x4*)(bnc + 1 * CC + c0);
    const f32x4 sxz = *(const f32x4*)(bnc + 2 * CC + c0);
    const f32x4 hxz = *(const f32x4*)(bnc + 3 * CC + c0);
    const f32x4 syz = *(const f32x4*)(bnc + 4 * CC + c0);
    const f32x4 hyz = *(const f32x4*)(bnc + 5 * CC + c0);
    const f32x4 al  = *(const f32x4*)(bnc + 6 * CC + c0);
    const f32x4 be  = *(const f32x4*)(bnc + 7 * CC + c0);

#pragma unroll
    for (int ph = 0; ph < 2; ++ph)
#pragma unroll
        for (int pw = 0; pw < 2; ++pw) {
            const f32x4 txy = axy[ph][pw] * sxy + hxy;
            const f32x4 txz = axz[ph][pw] * sxz + hxz;
            const f32x4 tyz = ayz[ph][pw] * syz + hyz;
            bf16x4 rr;
#pragma unroll
            for (int j = 0; j < 4; ++j) {
                const float fxy = fmaxf(txy[j], 0.f);
                const float fxz = fmaxf(txz[j], 0.f);
                const float fyz = fmaxf(tyz[j], 0.f);
                const float z   = al[j] * fxz + be[j] * fyz;
                const float g   = 1.f / (1.f + __expf(-z));
                rr[j] = (bf16)(fxy * g);  // fxy>=0, g>0 -> relu is a no-op
            }
            *(bf16x4*)(top + (plane + (size_t)(h0 + ph) * WW + (wb + pw)) * CC + c0) = rr;
        }
}

// ---------------------------------------------------------------------------
// K3: pw2 GEMM + BN + ReLU + SE partial sums.  Same K-split frame as K1.
// ---------------------------------------------------------------------------
__global__ __launch_bounds__(256, 3) void pw_gemm2(
    const bf16* __restrict__ top, const bf16* __restrict__ wbf,
    const float* __restrict__ g2, const float* __restrict__ b2,
    const float* __restrict__ m2, const float* __restrict__ v2,
    bf16* __restrict__ out2, float* __restrict__ sums)
{
    __shared__ __align__(16) bf16 XT[64][264];
    const int hw0 = blockIdx.x * 64;
    const int b   = blockIdx.y;
    const int t   = threadIdx.x;
    const int lane = t & 63, wv = t >> 6;
    const int q = lane >> 4, n = lane & 15;
    const int co_w = wv * 64;

    bf16x8 aq[4][4];
    const bf16* wp[4];
#pragma unroll
    for (int cf = 0; cf < 4; ++cf) {
        wp[cf] = wbf + (size_t)(co_w + cf * 16 + n) * CC + q * 8;
#pragma unroll
        for (int kx = 0; kx < 4; ++kx)
            aq[cf][kx] = *(const bf16x8*)(wp[cf] + kx * 32);
    }

    {   // straight copy staging (already NHWC): 64 bf16 per thread
        const int hw_r = t >> 2;
        const int k0   = (t & 3) * 64;
        const bf16* src = top + ((size_t)b * HWSZ + hw0 + hw_r) * CC + k0;
#pragma unroll
        for (int j = 0; j < 8; ++j)
            *(bf16x8*)(&XT[hw_r][k0 + j * 8]) = *(const bf16x8*)(src + j * 8);
    }
    __syncthreads();

    f32x4 acc[4][4] = {};
#pragma unroll
    for (int half = 0; half < 2; ++half) {
#pragma unroll
        for (int kx = 0; kx < 4; ++kx) {
            const int kk = half * 4 + kx;
            bf16x8 bq[4];
#pragma unroll
            for (int hf = 0; hf < 4; ++hf)
                bq[hf] = *(const bf16x8*)(&XT[hf * 16 + n][kk * 32 + q * 8]);
#pragma unroll
            for (int cf = 0; cf < 4; ++cf)
#pragma unroll
                for (int hf = 0; hf < 4; ++hf)
                    acc[cf][hf] = __builtin_amdgcn_mfma_f32_16x16x32_bf16(
                        aq[cf][kx], bq[hf], acc[cf][hf], 0, 0, 0);
        }
        if (half == 0) {
#pragma unroll
            for (int cf = 0; cf < 4; ++cf)
#pragma unroll
                for (int kx = 0; kx < 4; ++kx)
                    aq[cf][kx] = *(const bf16x8*)(wp[cf] + 128 + kx * 32);
        }
    }

    bf16* ob = out2 + ((size_t)b * HWSZ + hw0) * CC;
#pragma unroll
    for (int cf = 0; cf < 4; ++cf) {
        const int co4 = co_w + cf * 16 + q * 4;
        f32x4 g = *(const f32x4*)(g2 + co4);
        f32x4 bb = *(const f32x4*)(b2 + co4);
        f32x4 mm = *(const f32x4*)(m2 + co4);
        f32x4 vv = *(const f32x4*)(v2 + co4);
        f32x4 sc, sh;
#pragma unroll
        for (int r = 0; r < 4; ++r) {
            sc[r] = g[r] * rsqrtf(vv[r] + EPS);
            sh[r] = bb[r] - mm[r] * sc[r];
        }
        f32x4 rs = {};
#pragma unroll
        for (int hf = 0; hf < 4; ++hf) {
            bf16x4 r4;
#pragma unroll
            for (int r = 0; r < 4; ++r) {
                float v = fmaxf(acc[cf][hf][r] * sc[r] + sh[r], 0.f);
                rs[r] += v;
                r4[r] = (bf16)v;
            }
            *(bf16x4*)(ob + (size_t)(hf * 16 + n) * CC + co4) = r4;
        }
#pragma unroll
        for (int msk = 1; msk < 16; msk <<= 1)
#pragma unroll
            for (int r = 0; r < 4; ++r) rs[r] += __shfl_xor(rs[r], msk);
        if (n == 0) {
#pragma unroll
            for (int r = 0; r < 4; ++r)
                atomicAdd(&sums[b * CC + co4 + r], rs[r]);
        }
    }
}

// ---------------------------------------------------------------------------
// K5: SE FC (redundant per block, tiny) + apply + residual add + transpose.
// out[b][c][hw] = out2[b][hw][c] * scale[b,c] + x[b][c][hw]
// ---------------------------------------------------------------------------
__global__ __launch_bounds__(256) void se_apply(
    const bf16* __restrict__ out2, const float* __restrict__ x,
    const float* __restrict__ sums,
    const float* __restrict__ w1, const float* __restrict__ b1,
    const float* __restrict__ w2, const float* __restrict__ b2,
    float* __restrict__ out)
{
    __shared__ float TT[64 * 68];   // [c_local][hw_local], pad 68
    __shared__ float mean[256];
    __shared__ float hid[16];
    __shared__ __align__(16) float scl[64];
    const int hw0 = blockIdx.x * 64;
    const int c0  = blockIdx.y * 64;
    const int b   = blockIdx.z;
    const int t   = threadIdx.x;

    // --- SE FC (each block computes its 64-channel slice of scale) ---
    mean[t] = sums[b * CC + t] * (1.f / (float)HWSZ);
    __syncthreads();
    {
        const int m = t >> 4, l = t & 15;
        const float* wr = w1 + m * CC + l * 16;
        const float* mr = mean + l * 16;
        float h = 0.f;
#pragma unroll
        for (int j = 0; j < 16; ++j) h += wr[j] * mr[j];
#pragma unroll
        for (int msk = 1; msk < 16; msk <<= 1) h += __shfl_xor(h, msk);
        if (l == 0) hid[m] = fmaxf(h + b1[m], 0.f);
    }
    __syncthreads();
    if (t < 64) {
        const int c = c0 + t;
        float v = b2[c];
#pragma unroll
        for (int md = 0; md < 16; ++md) v += w2[c * 16 + md] * hid[md];
        scl[t] = 1.f / (1.f + __expf(-v));
    }
    __syncthreads();

    // --- scale + transpose via LDS ---
    {
        const int hw_r = t >> 2;
        const int coff = (t & 3) * 16;
        const bf16* p = out2 + ((size_t)b * HWSZ + hw0 + hw_r) * CC + c0 + coff;
        bf16x8 u0 = *(const bf16x8*)(p);
        bf16x8 u1 = *(const bf16x8*)(p + 8);
        f32x4 s0 = *(const f32x4*)(&scl[coff]);
        f32x4 s1 = *(const f32x4*)(&scl[coff + 4]);
        f32x4 s2 = *(const f32x4*)(&scl[coff + 8]);
        f32x4 s3 = *(const f32x4*)(&scl[coff + 12]);
#pragma unroll
        for (int j = 0; j < 4; ++j) {
            TT[(coff + j)      * 68 + hw_r] = (float)u0[j]     * s0[j];
            TT[(coff + 4 + j)  * 68 + hw_r] = (float)u0[4 + j] * s1[j];
            TT[(coff + 8 + j)  * 68 + hw_r] = (float)u1[j]     * s2[j];
            TT[(coff + 12 + j) * 68 + hw_r] = (float)u1[4 + j] * s3[j];
        }
    }
    __syncthreads();
    {
        const int c_r   = t >> 2;
        const int hwoff = (t & 3) * 16;
        const size_t go = ((size_t)b * CC + c0 + c_r) * HWSZ + hw0 + hwoff;
#pragma unroll
        for (int v = 0; v < 4; ++v) {
            f32x4 tv = *(const f32x4*)(&TT[c_r * 68 + hwoff + v * 4]);
            f32x4 xv = *(const f32x4*)(x + go + v * 4);
#pragma unroll
            for (int j = 0; j < 4; ++j) tv[j] += xv[j];
            *(f32x4*)(out + go + v * 4) = tv;
        }
    }
}

// ---------------------------------------------------------------------------
extern "C" void kernel_launch(void* const* d_in, const int* in_sizes, int n_in,
                              void* d_out, int out_size, void* d_ws, size_t ws_size,
                              hipStream_t stream)
{
    const float* x      = (const float*)d_in[0];
    const float* pw1_w  = (const float*)d_in[1];
    const float* xy3_w  = (const float*)d_in[2];
    const float* xy5_w  = (const float*)d_in[3];
    const float* bnxy_g = (const float*)d_in[4];
    const float* bnxy_b = (const float*)d_in[5];
    const float* bnxy_m = (const float*)d_in[6];
    const float* bnxy_v = (const float*)d_in[7];
    const float* xz3_w  = (const float*)d_in[8];
    const float* xz5_w  = (const float*)d_in[9];
    const float* bnxz_g = (const float*)d_in[10];
    const float* bnxz_b = (const float*)d_in[11];
    const float* bnxz_m = (const float*)d_in[12];
    const float* bnxz_v = (const float*)d_in[13];
    const float* yz3_w  = (const float*)d_in[14];
    const float* yz5_w  = (const float*)d_in[15];
    const float* bnyz_g = (const float*)d_in[16];
    const float* bnyz_b = (const float*)d_in[17];
    const float* bnyz_m = (const float*)d_in[18];
    const float* bnyz_v = (const float*)d_in[19];
    const float* alpha  = (const float*)d_in[20];
    const float* beta   = (const float*)d_in[21];
    const float* pw2_w  = (const float*)d_in[22];
    const float* bn2_g  = (const float*)d_in[23];
    const float* bn2_b  = (const float*)d_in[24];
    const float* bn2_m  = (const float*)d_in[25];
    const float* bn2_v  = (const float*)d_in[26];
    const float* fc1_w  = (const float*)d_in[27];
    const float* fc1_b  = (const float*)d_in[28];
    const float* fc2_w  = (const float*)d_in[29];
    const float* fc2_b  = (const float*)d_in[30];

    const size_t NEL = (size_t)BB * CC * HWSZ;   // 12,845,056
    char* ws = (char*)d_ws;
    float* sums  = (float*)(ws + OFF_SUMS);
    bf16*  wbf1  = (bf16*) (ws + OFF_WBF1);
    bf16*  wbf2  = (bf16*) (ws + OFF_WBF2);
    bf16*  wdw   = (bf16*) (ws + OFF_WDW);
    float* bnc   = (float*)(ws + OFF_BNC);
    bf16*  out2  = (bf16*) (ws + OFF_OUT2);
    bf16*  mid   = (bf16*)d_out;           // d_out as scratch: mid | top
    bf16*  top   = (bf16*)d_out + NEL;

    precast<<<257, 256, 0, stream>>>(pw1_w, pw2_w,
        xy3_w, xy5_w, xz3_w, xz5_w, yz3_w, yz5_w,
        bnxy_g, bnxy_b, bnxy_m, bnxy_v,
        bnxz_g, bnxz_b, bnxz_m, bnxz_v,
        bnyz_g, bnyz_b, bnyz_m, bnyz_v,
        alpha, beta, wbf1, wbf2, wdw, bnc, sums);

    pw_gemm1<<<dim3(49, 16), 256, 0, stream>>>(x, wbf1, mid);
    dwfuse<<<dim3(7, 28, 16), 256, 0, stream>>>(mid, wdw, bnc, top);
    pw_gemm2<<<dim3(49, 16), 256, 0, stream>>>(top, wbf2, bn2_g, bn2_b,
                                               bn2_m, bn2_v, out2, sums);
    se_apply<<<dim3(49, 4, 16), 256, 0, stream>>>(out2, x, sums,
        fc1_w, fc1_b, fc2_w, fc2_b, (float*)d_out);
}